// Round 17
// baseline (1508.464 us; speedup 1.0000x reference)
//
#include <hip/hip_runtime.h>
#include <hip/hip_bf16.h>

// ---- problem constants ----
static constexpr int B_ = 16;
static constexpr int N_ = 8192;
static constexpr int C_ = 32;     // input feature channels
static constexpr int S_ = 1024;   // NPOINT
static constexpr int K_ = 32;     // NSAMPLE
static constexpr float BN_EPS_ = 1e-5f;

typedef float f32x2 __attribute__((ext_vector_type(2)));

__device__ __forceinline__ unsigned short f2bf(float f){
  unsigned u = __float_as_uint(f);
  unsigned r = (u + 0x7fffu + ((u >> 16) & 1u)) >> 16;
  return (unsigned short)r;
}
__device__ __forceinline__ float bflo(unsigned u){ return __int_as_float(u << 16); }
__device__ __forceinline__ float bfhi(unsigned u){ return __int_as_float(u & 0xffff0000u); }
__device__ __forceinline__ float bfu(unsigned short u){ return __int_as_float(((unsigned)u) << 16); }

// rocPRIM-standard wave64 DPP reduce step on a u64 key (HW-proven R9-R16).
template<int CTRL>
__device__ __forceinline__ unsigned long long dpp64(unsigned long long v){
  int lo = (int)(unsigned)(v & 0xffffffffull);
  int hi = (int)(unsigned)(v >> 32);
  int lo2 = __builtin_amdgcn_update_dpp(lo, lo, CTRL, 0xf, 0xf, false);
  int hi2 = __builtin_amdgcn_update_dpp(hi, hi, CTRL, 0xf, 0xf, false);
  return (((unsigned long long)(unsigned)hi2) << 32) | (unsigned)lo2;
}
__device__ __forceinline__ unsigned long long u64max(unsigned long long a,
                                                     unsigned long long b){
  return a > b ? a : b;
}

// ---- features (B,C,N) f32 -> featT (B,N,C) bf16 ----
__global__ __launch_bounds__(256) void transpose_kernel(const float* __restrict__ feat,
                                                        unsigned short* __restrict__ featT){
  __shared__ float tile[32][33];
  const int b = blockIdx.y;
  const int n0 = blockIdx.x * 32;
  const int tx = threadIdx.x, ty = threadIdx.y;
#pragma unroll
  for (int i = 0; i < 4; i++){
    int c = ty + i * 8;
    tile[c][tx] = feat[((size_t)b * C_ + c) * N_ + n0 + tx];
  }
  __syncthreads();
#pragma unroll
  for (int i = 0; i < 4; i++){
    int r = ty + i * 8;
    featT[((size_t)b * N_ + n0 + r) * C_ + tx] = f2bf(tile[tx][r]);
  }
}

// ---- furthest point sampling: 1 block/batch, 256 threads, 1 barrier/iter ----
// R16 skeleton. Single change: the index-recovery scan is tree-ified — per-q
// candidate (same cmp/sel count) into 4 independent partial-min chains + a
// 2-level combine. Selection is bitwise identical: preference order
// (q0-lo, q0-hi, q1-lo, ...) is monotone increasing in global index, so
// min-over-matches == first-match; tmax is bitwise one of MD2 (fmin/fmax
// return operands exactly; squares >= +0; no NaN). Cuts a serial ~128-cycle
// cndmask dependency chain (unhidden at 1 wave/SIMD) to ~25 cycles.
__global__ __launch_bounds__(256) void fps_kernel(const float* __restrict__ xyz,
                                                  float* __restrict__ newxyz){
  const int b = blockIdx.x, t = threadIdx.x;      // t in [0,256)
  const float* px = xyz + (size_t)b * N_ * 3;
  __shared__ float pl[N_ * 3];                    // 96 KB copy of the batch
  __shared__ unsigned long long slots[2][4];      // [parity][wave]

  for (int i = t; i < N_ * 3 / 4; i += 256)
    ((float4*)pl)[i] = ((const float4*)px)[i];

  f32x2 X2[16], Y2[16], Z2[16], MD2[16];
#pragma unroll
  for (int q = 0; q < 16; q++){
    const int p0 = 512 * q + t, p1 = 512 * q + 256 + t;
    float x0 = px[3 * p0 + 0], y0 = px[3 * p0 + 1], z0 = px[3 * p0 + 2];
    float x1 = px[3 * p1 + 0], y1 = px[3 * p1 + 1], z1 = px[3 * p1 + 2];
    asm volatile("" : "+v"(x0), "+v"(y0), "+v"(z0),
                      "+v"(x1), "+v"(y1), "+v"(z1));   // pin SCALARS in VGPRs
    X2[q] = f32x2{x0, x1};
    Y2[q] = f32x2{y0, y1};
    Z2[q] = f32x2{z0, z1};
    MD2[q] = f32x2{1e10f, 1e10f};
  }
  if (t == 0){
    size_t o = (size_t)b * S_ * 3;
    newxyz[o] = px[0]; newxyz[o + 1] = px[1]; newxyz[o + 2] = px[2];
  }
  float cx = px[0], cy = px[1], cz = px[2];
  __syncthreads();                                // covers pl copy

  for (int i = 1; i < S_; i++){
    const int p = i & 1;
    const f32x2 cx2 = {cx, cx}, cy2 = {cy, cy}, cz2 = {cz, cz};
    float tmax = -1.f;
#pragma unroll
    for (int q = 0; q < 16; q++){
      f32x2 dx = X2[q] - cx2;                     // per-half rn sub
      f32x2 dy = Y2[q] - cy2;
      f32x2 dz = Z2[q] - cz2;
      f32x2 dd = (dx * dx + dy * dy) + dz * dz;   // exact reference op order
      f32x2 m;
      m[0] = fminf(MD2[q][0], dd[0]);
      m[1] = fminf(MD2[q][1], dd[1]);
      MD2[q] = m;
      tmax = fmaxf(tmax, fmaxf(m[0], m[1]));      // v_max3-fusable
    }
    // tree recovery of this thread's FIRST (smallest global) matching index
    unsigned part[4] = {65535u, 65535u, 65535u, 65535u};
#pragma unroll
    for (int q = 0; q < 16; q++){
      unsigned c0 = (MD2[q][0] == tmax) ? (unsigned)(512 * q + t)       : 65535u;
      unsigned c1 = (MD2[q][1] == tmax) ? (unsigned)(512 * q + 256 + t) : 65535u;
      unsigned cq = c0 < c1 ? c0 : c1;            // c0 < c1 when both match
      if (cq < part[q & 3]) part[q & 3] = cq;     // 4 independent chains
    }
    unsigned e0 = part[0] < part[1] ? part[0] : part[1];
    unsigned e1 = part[2] < part[3] ? part[2] : part[3];
    const unsigned cand = e0 < e1 ? e0 : e1;      // guaranteed a real match
    // key: larger value wins; tie -> larger (8191-idx) -> smaller idx.
    unsigned long long key = ((unsigned long long)__float_as_uint(tmax) << 32)
                           | (unsigned long long)(8191u - cand);
    key = u64max(key, dpp64<0xb1>(key));          // quad_perm [1,0,3,2]
    key = u64max(key, dpp64<0x4e>(key));          // quad_perm [2,3,0,1]
    key = u64max(key, dpp64<0x114>(key));         // row_shr:4
    key = u64max(key, dpp64<0x118>(key));         // row_shr:8
    key = u64max(key, dpp64<0x142>(key));         // row_bcast:15
    key = u64max(key, dpp64<0x143>(key));         // row_bcast:31
    if ((t & 63) == 63) slots[p][t >> 6] = key;   // plain write, 1 per wave
    __syncthreads();
    unsigned long long best = u64max(u64max(slots[p][0], slots[p][1]),
                                     u64max(slots[p][2], slots[p][3]));
    const int fi = 8191 - (int)(best & 0xffffu);
    cx = pl[3 * fi]; cy = pl[3 * fi + 1]; cz = pl[3 * fi + 2];  // LDS broadcast
    if (t == 0){
      size_t o = ((size_t)b * S_ + i) * 3;
      newxyz[o] = cx; newxyz[o + 1] = cy; newxyz[o + 2] = cz;
    }
  }
}

// ---- ball query: 1 wave per centroid ----
__global__ __launch_bounds__(256) void ballq_kernel(const float* __restrict__ xyz,
                                                    const float* __restrict__ newxyz,
                                                    int* __restrict__ idxout){
  const int wave = threadIdx.x >> 6, lane = threadIdx.x & 63;
  const int cid = blockIdx.x * 4 + wave;
  const int b = cid >> 10;
  const float cx = newxyz[(size_t)cid * 3];
  const float cy = newxyz[(size_t)cid * 3 + 1];
  const float cz = newxyz[(size_t)cid * 3 + 2];
  const float* px = xyz + (size_t)b * N_ * 3;
  __shared__ int buf[4][32];
  const float r2 = 0.04f;   // fp32(double(0.2*0.2)) == 0x3D23D70A
  int have = 0;
  for (int base = 0; base < N_ && have < 32; base += 64){
    int p = base + lane;
    float dx = __fsub_rn(cx, px[3 * p]);
    float dy = __fsub_rn(cy, px[3 * p + 1]);
    float dz = __fsub_rn(cz, px[3 * p + 2]);
    float sq = __fadd_rn(__fadd_rn(__fmul_rn(dx, dx), __fmul_rn(dy, dy)), __fmul_rn(dz, dz));
    bool pred = sq < r2;
    unsigned long long m = __ballot(pred);
    if (pred){
      int pos = have + __popcll(m & ((1ull << lane) - 1ull));
      if (pos < 32) buf[wave][pos] = p;
    }
    have += (int)__popcll(m);
  }
  __syncthreads();
  if (lane < 32){
    int first = buf[wave][0];
    int v = (lane < have) ? buf[wave][lane] : first;
    idxout[(size_t)cid * 32 + lane] = v;
  }
}

// ---- LDS arena layout for the recompute pass kernels (all f32) ----
// DEPTH==1 double-buffers the x tile (1 barrier/iter instead of 2).
template<int DEPTH>
struct PassLds {
  static constexpr int XSBUF = (DEPTH == 1) ? 2 : 1;
  static constexpr int XS  = 0;                       // [XSBUF][32][36] f32
  static constexpr int W1O = XS + XSBUF * 32 * 36;    // [64][36] f32 (col35 zeroed)
  static constexpr int HA  = W1O + 64 * 36;           // [32][68] f32 (DEPTH>=2)
  static constexpr int W2O = HA + 32 * 68;            // [64][64] f32, chunk-XOR swizzled
  static constexpr int HB  = W2O + 64 * 64;           // [32][68] f32 (DEPTH==3)
  static constexpr int W3O = HB + 32 * 68;            // [128][64] f32, chunk-XOR swizzled
  static constexpr int FLOATS = (DEPTH == 1) ? (W1O + 64 * 36)
                             : (DEPTH == 2) ? (W2O + 64 * 64)
                             : (W3O + 128 * 64);      // D3: 20096 floats = 80384 B
};

// ---- fused recompute pass (512 threads) ----
// Gather mapping: grow = t&31, ggrp = t>>5. Compute mapping: rb = t&15,
// og = t>>4 (register-blocked 2 rows x 2/4 outs; R16-proven). W2/W3 stored
// with 16B-chunk XOR swizzle. DEPTH==1: double-buffered xs, 1 barrier/iter.
template<int DEPTH, bool FT>
__global__ __launch_bounds__(512, 4) void pass_kernel(
    const float* __restrict__ xyz, const float* __restrict__ feat,
    const unsigned short* __restrict__ featT, const float* __restrict__ newxyz,
    const int* __restrict__ idx,
    const float* __restrict__ W1, const float* __restrict__ W2,
    const float* __restrict__ W3,
    const float* __restrict__ sab1, const float* __restrict__ sab2,
    float* __restrict__ partials,
    unsigned short* __restrict__ m3max, unsigned short* __restrict__ m3min){
  using L = PassLds<DEPTH>;
  __shared__ float sm[L::FLOATS];
  const int t = threadIdx.x;
  const int grow = t & 31, ggrp = t >> 5;   // gather mapping
  const int rb = t & 15, og = t >> 4;       // compute mapping (og in [0,32))

  // ---- stage weights once per block ----
  for (int i = t; i < 64 * 36; i += 512){
    int o = i / 36, c = i - o * 36;
    sm[L::W1O + i] = (c < 35) ? W1[o * 35 + c] : 0.f;
  }
  if constexpr (DEPTH >= 2){
    for (int i = t; i < 64 * 64; i += 512){
      int r = i >> 6, c = i & 63;
      sm[L::W2O + (r << 6) + ((((c >> 2) ^ ((r >> 1) & 3)) << 2) | (c & 3))] = W2[i];
    }
  }
  if constexpr (DEPTH == 3){
    for (int i = t; i < 128 * 64; i += 512){
      int r = i >> 6, c = i & 63;
      sm[L::W3O + (r << 6) + ((((c >> 2) ^ ((r >> 2) & 3)) << 2) | (c & 3))] = W3[i];
    }
  }

  // ---- per-thread BN params ----
  float sa1[2], sb1[2], sa2[2], sb2[2];
  if constexpr (DEPTH >= 2){
#pragma unroll
    for (int u = 0; u < 2; u++){ sa1[u] = sab1[og * 2 + u]; sb1[u] = sab1[64 + og * 2 + u]; }
  }
  if constexpr (DEPTH == 3){
#pragma unroll
    for (int u = 0; u < 2; u++){ sa2[u] = sab2[og * 2 + u]; sb2[u] = sab2[64 + og * 2 + u]; }
  }

  constexpr int US = (DEPTH == 3) ? 4 : 2;     // stats channels per thread
  float stS[US], stQ[US];
#pragma unroll
  for (int u = 0; u < US; u++){ stS[u] = 0.f; stQ[u] = 0.f; }

  // ---- prefetch state (registers) ----
  uint4 pfeat = {0, 0, 0, 0};
  float pf0 = 0.f, pf1 = 0.f, pf2 = 0.f, pf3 = 0.f;
  float prx = 0.f, pry = 0.f, prz = 0.f;

  auto prefetch = [&](int it2){
    const int g2 = blockIdx.x * 32 + it2;
    const int b2 = g2 >> 10;
    if constexpr (FT){
      if (ggrp < 4){
        const int id = idx[(size_t)g2 * 32 + grow];
        pfeat = *(const uint4*)(featT + ((size_t)b2 * N_ + id) * C_ + ggrp * 8);
      } else if (ggrp == 4){
        const int id = idx[(size_t)g2 * 32 + grow];
        size_t pb = ((size_t)b2 * N_ + id) * 3;
        prx = __fsub_rn(xyz[pb + 0], newxyz[(size_t)g2 * 3 + 0]);
        pry = __fsub_rn(xyz[pb + 1], newxyz[(size_t)g2 * 3 + 1]);
        prz = __fsub_rn(xyz[pb + 2], newxyz[(size_t)g2 * 3 + 2]);
      }
    } else {
      if (ggrp < 8){
        const int id = idx[(size_t)g2 * 32 + grow];
        pf0 = feat[((size_t)b2 * C_ + ggrp * 4 + 0) * N_ + id];
        pf1 = feat[((size_t)b2 * C_ + ggrp * 4 + 1) * N_ + id];
        pf2 = feat[((size_t)b2 * C_ + ggrp * 4 + 2) * N_ + id];
        pf3 = feat[((size_t)b2 * C_ + ggrp * 4 + 3) * N_ + id];
      } else if (ggrp == 8){
        const int id = idx[(size_t)g2 * 32 + grow];
        size_t pb = ((size_t)b2 * N_ + id) * 3;
        prx = __fsub_rn(xyz[pb + 0], newxyz[(size_t)g2 * 3 + 0]);
        pry = __fsub_rn(xyz[pb + 1], newxyz[(size_t)g2 * 3 + 1]);
        prz = __fsub_rn(xyz[pb + 2], newxyz[(size_t)g2 * 3 + 2]);
      }
    }
  };
  auto commit_xs = [&](int buf){
    float* xr = &sm[L::XS + buf * (32 * 36) + grow * 36];
    if constexpr (FT){
      if (ggrp < 4){
        xr[3 + ggrp * 8 + 0] = bflo(pfeat.x); xr[3 + ggrp * 8 + 1] = bfhi(pfeat.x);
        xr[3 + ggrp * 8 + 2] = bflo(pfeat.y); xr[3 + ggrp * 8 + 3] = bfhi(pfeat.y);
        xr[3 + ggrp * 8 + 4] = bflo(pfeat.z); xr[3 + ggrp * 8 + 5] = bfhi(pfeat.z);
        xr[3 + ggrp * 8 + 6] = bflo(pfeat.w); xr[3 + ggrp * 8 + 7] = bfhi(pfeat.w);
      } else if (ggrp == 4){
        xr[0] = prx; xr[1] = pry; xr[2] = prz; xr[35] = 0.f;
      }
    } else {
      if (ggrp < 8){
        xr[3 + ggrp * 4 + 0] = pf0; xr[3 + ggrp * 4 + 1] = pf1;
        xr[3 + ggrp * 4 + 2] = pf2; xr[3 + ggrp * 4 + 3] = pf3;
      } else if (ggrp == 8){
        xr[0] = prx; xr[1] = pry; xr[2] = prz; xr[35] = 0.f;
      }
    }
  };

  prefetch(0);
  commit_xs(0);
  __syncthreads();    // covers weights + xs(0)

  for (int it = 0; it < 32; ++it){
    const int g = blockIdx.x * 32 + it;
    const int b = g >> 10;
    const int xbuf = (DEPTH == 1) ? (it & 1) : 0;
    if (it < 31) prefetch(it + 1);              // issue next group's loads

    // ---- mm1: rows {rb, rb+16} x outs {og*2, og*2+1} ----
    const int xbase = L::XS + xbuf * (32 * 36);
    float a00 = 0.f, a01 = 0.f, a10 = 0.f, a11 = 0.f;
#pragma unroll 3
    for (int cb = 0; cb < 36; cb += 4){
      const float4 x0 = *(const float4*)&sm[xbase + rb * 36 + cb];
      const float4 x1 = *(const float4*)&sm[xbase + (rb + 16) * 36 + cb];
      const float4 w0 = *(const float4*)&sm[L::W1O + (og * 2 + 0) * 36 + cb];
      const float4 w1 = *(const float4*)&sm[L::W1O + (og * 2 + 1) * 36 + cb];
      a00 = fmaf(x0.x, w0.x, a00); a00 = fmaf(x0.y, w0.y, a00);
      a00 = fmaf(x0.z, w0.z, a00); a00 = fmaf(x0.w, w0.w, a00);
      a01 = fmaf(x0.x, w1.x, a01); a01 = fmaf(x0.y, w1.y, a01);
      a01 = fmaf(x0.z, w1.z, a01); a01 = fmaf(x0.w, w1.w, a01);
      a10 = fmaf(x1.x, w0.x, a10); a10 = fmaf(x1.y, w0.y, a10);
      a10 = fmaf(x1.z, w0.z, a10); a10 = fmaf(x1.w, w0.w, a10);
      a11 = fmaf(x1.x, w1.x, a11); a11 = fmaf(x1.y, w1.y, a11);
      a11 = fmaf(x1.z, w1.z, a11); a11 = fmaf(x1.w, w1.w, a11);
    }
    if constexpr (DEPTH == 1){
      stS[0] += a00 + a10; stQ[0] = fmaf(a00, a00, stQ[0]); stQ[0] = fmaf(a10, a10, stQ[0]);
      stS[1] += a01 + a11; stQ[1] = fmaf(a01, a01, stQ[1]); stQ[1] = fmaf(a11, a11, stQ[1]);
      if (it < 31) commit_xs(xbuf ^ 1);         // disjoint buffer: no hazard
      __syncthreads();                          // xs(it+1) visible; WAR ordered
      continue;
    }

    // ---- bn1 + relu -> hA ----
    sm[L::HA + rb * 68 + og * 2 + 0]        = fmaxf(fmaf(a00, sa1[0], sb1[0]), 0.f);
    sm[L::HA + rb * 68 + og * 2 + 1]        = fmaxf(fmaf(a01, sa1[1], sb1[1]), 0.f);
    sm[L::HA + (rb + 16) * 68 + og * 2 + 0] = fmaxf(fmaf(a10, sa1[0], sb1[0]), 0.f);
    sm[L::HA + (rb + 16) * 68 + og * 2 + 1] = fmaxf(fmaf(a11, sa1[1], sb1[1]), 0.f);
    __syncthreads();                            // HA ready; xs dead
    if (it < 31) commit_xs(0);                  // overlap with mm2/mm3

    // ---- mm2: rows {rb, rb+16} x outs {og*2, og*2+1}, W2 swizzled ----
    float c00 = 0.f, c01 = 0.f, c10 = 0.f, c11 = 0.f;
#pragma unroll 4
    for (int cb = 0; cb < 64; cb += 4){
      const float4 x0 = *(const float4*)&sm[L::HA + rb * 68 + cb];
      const float4 x1 = *(const float4*)&sm[L::HA + (rb + 16) * 68 + cb];
      const int r0 = og * 2 + 0, r1 = og * 2 + 1;
      const float4 w0 = *(const float4*)&sm[L::W2O + (r0 << 6) + (((cb >> 2) ^ ((r0 >> 1) & 3)) << 2)];
      const float4 w1 = *(const float4*)&sm[L::W2O + (r1 << 6) + (((cb >> 2) ^ ((r1 >> 1) & 3)) << 2)];
      c00 = fmaf(x0.x, w0.x, c00); c00 = fmaf(x0.y, w0.y, c00);
      c00 = fmaf(x0.z, w0.z, c00); c00 = fmaf(x0.w, w0.w, c00);
      c01 = fmaf(x0.x, w1.x, c01); c01 = fmaf(x0.y, w1.y, c01);
      c01 = fmaf(x0.z, w1.z, c01); c01 = fmaf(x0.w, w1.w, c01);
      c10 = fmaf(x1.x, w0.x, c10); c10 = fmaf(x1.y, w0.y, c10);
      c10 = fmaf(x1.z, w0.z, c10); c10 = fmaf(x1.w, w0.w, c10);
      c11 = fmaf(x1.x, w1.x, c11); c11 = fmaf(x1.y, w1.y, c11);
      c11 = fmaf(x1.z, w1.z, c11); c11 = fmaf(x1.w, w1.w, c11);
    }
    if constexpr (DEPTH == 2){
      stS[0] += c00 + c10; stQ[0] = fmaf(c00, c00, stQ[0]); stQ[0] = fmaf(c10, c10, stQ[0]);
      stS[1] += c01 + c11; stQ[1] = fmaf(c01, c01, stQ[1]); stQ[1] = fmaf(c11, c11, stQ[1]);
      __syncthreads();                          // orders xs commit + HA reuse
      continue;
    }

    if constexpr (DEPTH == 3){
      // ---- bn2 + relu -> hB ----
      sm[L::HB + rb * 68 + og * 2 + 0]        = fmaxf(fmaf(c00, sa2[0], sb2[0]), 0.f);
      sm[L::HB + rb * 68 + og * 2 + 1]        = fmaxf(fmaf(c01, sa2[1], sb2[1]), 0.f);
      sm[L::HB + (rb + 16) * 68 + og * 2 + 0] = fmaxf(fmaf(c10, sa2[0], sb2[0]), 0.f);
      sm[L::HB + (rb + 16) * 68 + og * 2 + 1] = fmaxf(fmaf(c11, sa2[1], sb2[1]), 0.f);
      __syncthreads();                          // HB ready; xs commit visible

      // ---- mm3: rows {rb, rb+16} x outs {og*4..og*4+3}, W3 swizzled ----
      float d0[4] = {0.f, 0.f, 0.f, 0.f};
      float d1[4] = {0.f, 0.f, 0.f, 0.f};
#pragma unroll 2
      for (int cb = 0; cb < 64; cb += 4){
        const float4 x0 = *(const float4*)&sm[L::HB + rb * 68 + cb];
        const float4 x1 = *(const float4*)&sm[L::HB + (rb + 16) * 68 + cb];
#pragma unroll
        for (int u = 0; u < 4; u++){
          const int r = og * 4 + u;
          const float4 wv = *(const float4*)&sm[L::W3O + (r << 6) + (((cb >> 2) ^ ((r >> 2) & 3)) << 2)];
          d0[u] = fmaf(x0.x, wv.x, d0[u]); d0[u] = fmaf(x0.y, wv.y, d0[u]);
          d0[u] = fmaf(x0.z, wv.z, d0[u]); d0[u] = fmaf(x0.w, wv.w, d0[u]);
          d1[u] = fmaf(x1.x, wv.x, d1[u]); d1[u] = fmaf(x1.y, wv.y, d1[u]);
          d1[u] = fmaf(x1.z, wv.z, d1[u]); d1[u] = fmaf(x1.w, wv.w, d1[u]);
        }
      }
#pragma unroll
      for (int u = 0; u < 4; u++){
        stS[u] += d0[u] + d1[u];
        stQ[u] = fmaf(d0[u], d0[u], stQ[u]);
        stQ[u] = fmaf(d1[u], d1[u], stQ[u]);
      }

      // ---- pre-BN max/min over the 32 rows (16 rb lanes x 2 rows) ----
      const int s = g & 1023;
#pragma unroll
      for (int u = 0; u < 4; u++){
        float mx = fmaxf(d0[u], d1[u]);
        float mn = fminf(d0[u], d1[u]);
#pragma unroll
        for (int m = 1; m < 16; m <<= 1){
          mx = fmaxf(mx, __shfl_xor(mx, m));
          mn = fminf(mn, __shfl_xor(mn, m));
        }
        if (rb == 0){
          size_t o = ((size_t)b * 128 + og * 4 + u) * 1024 + s;
          m3max[o] = f2bf(mx); m3min[o] = f2bf(mn);
        }
      }
    }
  }

  // ---- block stats partials: reduce over the 16 rb lanes ----
#pragma unroll
  for (int m = 1; m < 16; m <<= 1){
#pragma unroll
    for (int u = 0; u < US; u++){
      stS[u] += __shfl_xor(stS[u], m);
      stQ[u] += __shfl_xor(stQ[u], m);
    }
  }
  if (rb == 0){
    constexpr int CH = (DEPTH == 3) ? 128 : 64;
    float* p = partials + (size_t)blockIdx.x * (2 * CH);
    const int o0 = og * US;
#pragma unroll
    for (int u = 0; u < US; u++){ p[o0 + u] = stS[u]; p[CH + o0 + u] = stQ[u]; }
  }
}

// ---- stats stage 2: reduce 512 partial rows, emit per-channel scale/shift ----
template<int CH>
__global__ __launch_bounds__(256) void stats_fin(const float* __restrict__ partials,
                                                 const float* __restrict__ g,
                                                 const float* __restrict__ bet,
                                                 float* __restrict__ sab){
  const int t = threadIdx.x;
  __shared__ float red[2 * CH];
  if (t < 2 * CH){
    float a = 0.f;
#pragma unroll 8
    for (int r = 0; r < 512; r++) a += partials[(size_t)r * (2 * CH) + t];
    red[t] = a;
  }
  __syncthreads();
  if (t < CH){
    constexpr float inv = 1.f / (float)((size_t)B_ * S_ * K_);
    float mean = red[t] * inv;
    float var  = red[CH + t] * inv - mean * mean;
    float r    = 1.f / sqrtf(var + BN_EPS_);
    float a    = r * g[t];
    sab[t] = a;
    sab[CH + t] = bet[t] - mean * a;
  }
}

// ---- final: bn3(+relu) on bf16 pre-BN max/min (monotone-affine dispatch) ----
__global__ __launch_bounds__(256) void final_kernel(const unsigned short* __restrict__ m3max,
                                                    const unsigned short* __restrict__ m3min,
                                                    const float* __restrict__ sab3,
                                                    float* __restrict__ outNF){
  const int q = blockIdx.x * 256 + threadIdx.x;   // quad index over B*128*1024/4
  const int e = q * 4;
  const int o = (e >> 10) & 127;
  const float a = sab3[o], c = sab3[128 + o];
  const ushort4 mx = ((const ushort4*)m3max)[q];
  const ushort4 mn = ((const ushort4*)m3min)[q];
  float4 r;
  r.x = fmaxf(fmaf(bfu(a >= 0.f ? mx.x : mn.x), a, c), 0.f);
  r.y = fmaxf(fmaf(bfu(a >= 0.f ? mx.y : mn.y), a, c), 0.f);
  r.z = fmaxf(fmaf(bfu(a >= 0.f ? mx.z : mn.z), a, c), 0.f);
  r.w = fmaxf(fmaf(bfu(a >= 0.f ? mx.w : mn.w), a, c), 0.f);
  ((float4*)outNF)[q] = r;
}

extern "C" void kernel_launch(void* const* d_in, const int* in_sizes, int n_in,
                              void* d_out, int out_size, void* d_ws, size_t ws_size,
                              hipStream_t stream){
  (void)in_sizes; (void)n_in; (void)out_size;
  const float* xyz = (const float*)d_in[0];
  const float* feat = (const float*)d_in[1];
  const float* W1 = (const float*)d_in[2];
  const float* g1 = (const float*)d_in[3];
  const float* b1 = (const float*)d_in[4];
  const float* W2 = (const float*)d_in[5];
  const float* g2 = (const float*)d_in[6];
  const float* b2 = (const float*)d_in[7];
  const float* W3 = (const float*)d_in[8];
  const float* g3 = (const float*)d_in[9];
  const float* b3 = (const float*)d_in[10];

  float* newxyz = (float*)d_out;                       // (B,S,3)
  float* outNF  = newxyz + (size_t)B_ * S_ * 3;        // (B,128,S)
  char* ws = (char*)d_ws;

  size_t off = 0;
  auto alloc = [&](size_t bytes){ size_t o = off; off += (bytes + 255) & ~(size_t)255; return o; };
  size_t o_idx  = alloc((size_t)B_ * S_ * K_ * 4);           // 2 MB
  size_t o_part = alloc((size_t)512 * 256 * 4);              // 512 KB
  size_t o_sab1 = alloc(1024);
  size_t o_sab2 = alloc(1024);
  size_t o_sab3 = alloc(1024);
  size_t o_m3mx = alloc((size_t)B_ * S_ * 128 * 2);          // 4 MB (bf16)
  size_t o_m3mn = alloc((size_t)B_ * S_ * 128 * 2);          // 4 MB (bf16)
  size_t o_featT = alloc((size_t)B_ * N_ * C_ * 2);          // 8 MB (bf16)
  const bool ft = ws_size >= off;                            // 19.4 MB total

  int*   idxp  = (int*)(ws + o_idx);
  float* part  = (float*)(ws + o_part);
  float* sab1  = (float*)(ws + o_sab1);
  float* sab2  = (float*)(ws + o_sab2);
  float* sab3  = (float*)(ws + o_sab3);
  unsigned short* m3mx  = (unsigned short*)(ws + o_m3mx);
  unsigned short* m3mn  = (unsigned short*)(ws + o_m3mn);
  unsigned short* featT = (unsigned short*)(ws + o_featT);

  if (ft) transpose_kernel<<<dim3(N_ / 32, B_), dim3(32, 8), 0, stream>>>(feat, featT);
  fps_kernel<<<B_, 256, 0, stream>>>(xyz, newxyz);
  ballq_kernel<<<B_ * S_ / 4, 256, 0, stream>>>(xyz, newxyz, idxp);

  if (ft){
    pass_kernel<1, true><<<512, 512, 0, stream>>>(xyz, feat, featT, newxyz, idxp,
        W1, W2, W3, sab1, sab2, part, m3mx, m3mn);
    stats_fin<64><<<1, 256, 0, stream>>>(part, g1, b1, sab1);
    pass_kernel<2, true><<<512, 512, 0, stream>>>(xyz, feat, featT, newxyz, idxp,
        W1, W2, W3, sab1, sab2, part, m3mx, m3mn);
    stats_fin<64><<<1, 256, 0, stream>>>(part, g2, b2, sab2);
    pass_kernel<3, true><<<512, 512, 0, stream>>>(xyz, feat, featT, newxyz, idxp,
        W1, W2, W3, sab1, sab2, part, m3mx, m3mn);
    stats_fin<128><<<1, 256, 0, stream>>>(part, g3, b3, sab3);
  } else {
    pass_kernel<1, false><<<512, 512, 0, stream>>>(xyz, feat, featT, newxyz, idxp,
        W1, W2, W3, sab1, sab2, part, m3mx, m3mn);
    stats_fin<64><<<1, 256, 0, stream>>>(part, g1, b1, sab1);
    pass_kernel<2, false><<<512, 512, 0, stream>>>(xyz, feat, featT, newxyz, idxp,
        W1, W2, W3, sab1, sab2, part, m3mx, m3mn);
    stats_fin<64><<<1, 256, 0, stream>>>(part, g2, b2, sab2);
    pass_kernel<3, false><<<512, 512, 0, stream>>>(xyz, feat, featT, newxyz, idxp,
        W1, W2, W3, sab1, sab2, part, m3mx, m3mn);
    stats_fin<128><<<1, 256, 0, stream>>>(part, g3, b3, sab3);
  }
  final_kernel<<<(B_ * 128 * S_) / 1024, 256, 0, stream>>>(m3mx, m3mn, sab3, outNF);
}

// Round 18
// 1490.183 us; speedup vs baseline: 1.0123x; 1.0123x over previous
//
#include <hip/hip_runtime.h>
#include <hip/hip_bf16.h>

// ---- problem constants ----
static constexpr int B_ = 16;
static constexpr int N_ = 8192;
static constexpr int C_ = 32;     // input feature channels
static constexpr int S_ = 1024;   // NPOINT
static constexpr int K_ = 32;     // NSAMPLE
static constexpr float BN_EPS_ = 1e-5f;

typedef float f32x2 __attribute__((ext_vector_type(2)));

__device__ __forceinline__ unsigned short f2bf(float f){
  unsigned u = __float_as_uint(f);
  unsigned r = (u + 0x7fffu + ((u >> 16) & 1u)) >> 16;
  return (unsigned short)r;
}
__device__ __forceinline__ float bflo(unsigned u){ return __int_as_float(u << 16); }
__device__ __forceinline__ float bfhi(unsigned u){ return __int_as_float(u & 0xffff0000u); }
__device__ __forceinline__ float bfu(unsigned short u){ return __int_as_float(((unsigned)u) << 16); }

// rocPRIM-standard wave64 DPP reduce step on a u64 key (HW-proven R9-R17).
template<int CTRL>
__device__ __forceinline__ unsigned long long dpp64(unsigned long long v){
  int lo = (int)(unsigned)(v & 0xffffffffull);
  int hi = (int)(unsigned)(v >> 32);
  int lo2 = __builtin_amdgcn_update_dpp(lo, lo, CTRL, 0xf, 0xf, false);
  int hi2 = __builtin_amdgcn_update_dpp(hi, hi, CTRL, 0xf, 0xf, false);
  return (((unsigned long long)(unsigned)hi2) << 32) | (unsigned)lo2;
}
__device__ __forceinline__ unsigned long long u64max(unsigned long long a,
                                                     unsigned long long b){
  return a > b ? a : b;
}

// ---- fused FPS + transpose: blocks [0,16) run FPS (R16 HW-proven body,
// 883.8 us); blocks [16,4112) transpose feat (B,C,N) f32 -> featT (B,N,C)
// bf16, hidden in FPS's shadow (FPS occupies only 16 of 256 CUs). The
// transpose tile reuses the 96 KB pl array. Stream order guarantees featT
// is complete before pass1 reads it (same kernel).
__global__ __launch_bounds__(256) void fps_trans_kernel(
    const float* __restrict__ xyz, float* __restrict__ newxyz,
    const float* __restrict__ feat, unsigned short* __restrict__ featT){
  __shared__ float pl[N_ * 3];                    // FPS: batch copy; T: tile
  __shared__ unsigned long long slots[2][4];      // [parity][wave]

  if (blockIdx.x >= 16){
    // ---- transpose role ----
    const int tb = blockIdx.x - 16;               // [0,4096)
    const int b = tb >> 8;
    const int n0 = (tb & 255) * 32;
    const int tx = threadIdx.x & 31, ty = threadIdx.x >> 5;
#pragma unroll
    for (int i = 0; i < 4; i++){
      int c = ty + i * 8;
      pl[c * 33 + tx] = feat[((size_t)b * C_ + c) * N_ + n0 + tx];
    }
    __syncthreads();
#pragma unroll
    for (int i = 0; i < 4; i++){
      int r = ty + i * 8;
      featT[((size_t)b * N_ + n0 + r) * C_ + tx] = f2bf(pl[tx * 33 + r]);
    }
    return;
  }

  // ---- FPS role (exact R16 body: descending recovery scan) ----
  const int b = blockIdx.x, t = threadIdx.x;      // t in [0,256)
  const float* px = xyz + (size_t)b * N_ * 3;

  for (int i = t; i < N_ * 3 / 4; i += 256)
    ((float4*)pl)[i] = ((const float4*)px)[i];

  f32x2 X2[16], Y2[16], Z2[16], MD2[16];
#pragma unroll
  for (int q = 0; q < 16; q++){
    const int p0 = 512 * q + t, p1 = 512 * q + 256 + t;
    float x0 = px[3 * p0 + 0], y0 = px[3 * p0 + 1], z0 = px[3 * p0 + 2];
    float x1 = px[3 * p1 + 0], y1 = px[3 * p1 + 1], z1 = px[3 * p1 + 2];
    asm volatile("" : "+v"(x0), "+v"(y0), "+v"(z0),
                      "+v"(x1), "+v"(y1), "+v"(z1));   // pin SCALARS in VGPRs
    X2[q] = f32x2{x0, x1};
    Y2[q] = f32x2{y0, y1};
    Z2[q] = f32x2{z0, z1};
    MD2[q] = f32x2{1e10f, 1e10f};
  }
  if (t == 0){
    size_t o = (size_t)b * S_ * 3;
    newxyz[o] = px[0]; newxyz[o + 1] = px[1]; newxyz[o + 2] = px[2];
  }
  float cx = px[0], cy = px[1], cz = px[2];
  __syncthreads();                                // covers pl copy

  for (int i = 1; i < S_; i++){
    const int p = i & 1;
    const f32x2 cx2 = {cx, cx}, cy2 = {cy, cy}, cz2 = {cz, cz};
    float tmax = -1.f;
#pragma unroll
    for (int q = 0; q < 16; q++){
      f32x2 dx = X2[q] - cx2;                     // per-half rn sub
      f32x2 dy = Y2[q] - cy2;
      f32x2 dz = Z2[q] - cz2;
      f32x2 dd = (dx * dx + dy * dy) + dz * dz;   // exact reference op order
      f32x2 m;
      m[0] = fminf(MD2[q][0], dd[0]);
      m[1] = fminf(MD2[q][1], dd[1]);
      MD2[q] = m;
      tmax = fmaxf(tmax, fmaxf(m[0], m[1]));      // v_max3-fusable
    }
    // recover this thread's FIRST (smallest global) index attaining tmax:
    // descending q, high half before low half -> later (smaller) overwrite.
    unsigned cand = 0;
#pragma unroll
    for (int q = 15; q >= 0; q--){
      if (MD2[q][1] == tmax) cand = (unsigned)(512 * q + 256 + t);
      if (MD2[q][0] == tmax) cand = (unsigned)(512 * q + t);
    }
    // key: larger value wins; tie -> larger (8191-idx) -> smaller idx.
    unsigned long long key = ((unsigned long long)__float_as_uint(tmax) << 32)
                           | (unsigned long long)(8191u - cand);
    key = u64max(key, dpp64<0xb1>(key));          // quad_perm [1,0,3,2]
    key = u64max(key, dpp64<0x4e>(key));          // quad_perm [2,3,0,1]
    key = u64max(key, dpp64<0x114>(key));         // row_shr:4
    key = u64max(key, dpp64<0x118>(key));         // row_shr:8
    key = u64max(key, dpp64<0x142>(key));         // row_bcast:15
    key = u64max(key, dpp64<0x143>(key));         // row_bcast:31
    if ((t & 63) == 63) slots[p][t >> 6] = key;   // plain write, 1 per wave
    __syncthreads();
    unsigned long long best = u64max(u64max(slots[p][0], slots[p][1]),
                                     u64max(slots[p][2], slots[p][3]));
    const int fi = 8191 - (int)(best & 0xffffu);
    cx = pl[3 * fi]; cy = pl[3 * fi + 1]; cz = pl[3 * fi + 2];  // LDS broadcast
    if (t == 0){
      size_t o = ((size_t)b * S_ + i) * 3;
      newxyz[o] = cx; newxyz[o + 1] = cy; newxyz[o + 2] = cz;
    }
  }
}

// ---- ball query: 1 wave per centroid ----
__global__ __launch_bounds__(256) void ballq_kernel(const float* __restrict__ xyz,
                                                    const float* __restrict__ newxyz,
                                                    int* __restrict__ idxout){
  const int wave = threadIdx.x >> 6, lane = threadIdx.x & 63;
  const int cid = blockIdx.x * 4 + wave;
  const int b = cid >> 10;
  const float cx = newxyz[(size_t)cid * 3];
  const float cy = newxyz[(size_t)cid * 3 + 1];
  const float cz = newxyz[(size_t)cid * 3 + 2];
  const float* px = xyz + (size_t)b * N_ * 3;
  __shared__ int buf[4][32];
  const float r2 = 0.04f;   // fp32(double(0.2*0.2)) == 0x3D23D70A
  int have = 0;
  for (int base = 0; base < N_ && have < 32; base += 64){
    int p = base + lane;
    float dx = __fsub_rn(cx, px[3 * p]);
    float dy = __fsub_rn(cy, px[3 * p + 1]);
    float dz = __fsub_rn(cz, px[3 * p + 2]);
    float sq = __fadd_rn(__fadd_rn(__fmul_rn(dx, dx), __fmul_rn(dy, dy)), __fmul_rn(dz, dz));
    bool pred = sq < r2;
    unsigned long long m = __ballot(pred);
    if (pred){
      int pos = have + __popcll(m & ((1ull << lane) - 1ull));
      if (pos < 32) buf[wave][pos] = p;
    }
    have += (int)__popcll(m);
  }
  __syncthreads();
  if (lane < 32){
    int first = buf[wave][0];
    int v = (lane < have) ? buf[wave][lane] : first;
    idxout[(size_t)cid * 32 + lane] = v;
  }
}

// ---- LDS arena layout for the recompute pass kernels (all f32) ----
// DEPTH==1 double-buffers the x tile (1 barrier/iter instead of 2).
template<int DEPTH>
struct PassLds {
  static constexpr int XSBUF = (DEPTH == 1) ? 2 : 1;
  static constexpr int XS  = 0;                       // [XSBUF][32][36] f32
  static constexpr int W1O = XS + XSBUF * 32 * 36;    // [64][36] f32 (col35 zeroed)
  static constexpr int HA  = W1O + 64 * 36;           // [32][68] f32 (DEPTH>=2)
  static constexpr int W2O = HA + 32 * 68;            // [64][64] f32, chunk-XOR swizzled
  static constexpr int HB  = W2O + 64 * 64;           // [32][68] f32 (DEPTH==3)
  static constexpr int W3O = HB + 32 * 68;            // [128][64] f32, chunk-XOR swizzled
  static constexpr int FLOATS = (DEPTH == 1) ? (W1O + 64 * 36)
                             : (DEPTH == 2) ? (W2O + 64 * 64)
                             : (W3O + 128 * 64);      // D3: 20096 floats = 80384 B
};

// ---- fused recompute pass (512 threads) ----
// Gather mapping: grow = t&31, ggrp = t>>5. Compute mapping: rb = t&15,
// og = t>>4 (register-blocked 2 rows x 2/4 outs; R16-proven). W2/W3 stored
// with 16B-chunk XOR swizzle. DEPTH==1: double-buffered xs, 1 barrier/iter.
template<int DEPTH, bool FT>
__global__ __launch_bounds__(512, 4) void pass_kernel(
    const float* __restrict__ xyz, const float* __restrict__ feat,
    const unsigned short* __restrict__ featT, const float* __restrict__ newxyz,
    const int* __restrict__ idx,
    const float* __restrict__ W1, const float* __restrict__ W2,
    const float* __restrict__ W3,
    const float* __restrict__ sab1, const float* __restrict__ sab2,
    float* __restrict__ partials,
    unsigned short* __restrict__ m3max, unsigned short* __restrict__ m3min){
  using L = PassLds<DEPTH>;
  __shared__ float sm[L::FLOATS];
  const int t = threadIdx.x;
  const int grow = t & 31, ggrp = t >> 5;   // gather mapping
  const int rb = t & 15, og = t >> 4;       // compute mapping (og in [0,32))

  // ---- stage weights once per block ----
  for (int i = t; i < 64 * 36; i += 512){
    int o = i / 36, c = i - o * 36;
    sm[L::W1O + i] = (c < 35) ? W1[o * 35 + c] : 0.f;
  }
  if constexpr (DEPTH >= 2){
    for (int i = t; i < 64 * 64; i += 512){
      int r = i >> 6, c = i & 63;
      sm[L::W2O + (r << 6) + ((((c >> 2) ^ ((r >> 1) & 3)) << 2) | (c & 3))] = W2[i];
    }
  }
  if constexpr (DEPTH == 3){
    for (int i = t; i < 128 * 64; i += 512){
      int r = i >> 6, c = i & 63;
      sm[L::W3O + (r << 6) + ((((c >> 2) ^ ((r >> 2) & 3)) << 2) | (c & 3))] = W3[i];
    }
  }

  // ---- per-thread BN params ----
  float sa1[2], sb1[2], sa2[2], sb2[2];
  if constexpr (DEPTH >= 2){
#pragma unroll
    for (int u = 0; u < 2; u++){ sa1[u] = sab1[og * 2 + u]; sb1[u] = sab1[64 + og * 2 + u]; }
  }
  if constexpr (DEPTH == 3){
#pragma unroll
    for (int u = 0; u < 2; u++){ sa2[u] = sab2[og * 2 + u]; sb2[u] = sab2[64 + og * 2 + u]; }
  }

  constexpr int US = (DEPTH == 3) ? 4 : 2;     // stats channels per thread
  float stS[US], stQ[US];
#pragma unroll
  for (int u = 0; u < US; u++){ stS[u] = 0.f; stQ[u] = 0.f; }

  // ---- prefetch state (registers) ----
  uint4 pfeat = {0, 0, 0, 0};
  float pf0 = 0.f, pf1 = 0.f, pf2 = 0.f, pf3 = 0.f;
  float prx = 0.f, pry = 0.f, prz = 0.f;

  auto prefetch = [&](int it2){
    const int g2 = blockIdx.x * 32 + it2;
    const int b2 = g2 >> 10;
    if constexpr (FT){
      if (ggrp < 4){
        const int id = idx[(size_t)g2 * 32 + grow];
        pfeat = *(const uint4*)(featT + ((size_t)b2 * N_ + id) * C_ + ggrp * 8);
      } else if (ggrp == 4){
        const int id = idx[(size_t)g2 * 32 + grow];
        size_t pb = ((size_t)b2 * N_ + id) * 3;
        prx = __fsub_rn(xyz[pb + 0], newxyz[(size_t)g2 * 3 + 0]);
        pry = __fsub_rn(xyz[pb + 1], newxyz[(size_t)g2 * 3 + 1]);
        prz = __fsub_rn(xyz[pb + 2], newxyz[(size_t)g2 * 3 + 2]);
      }
    } else {
      if (ggrp < 8){
        const int id = idx[(size_t)g2 * 32 + grow];
        pf0 = feat[((size_t)b2 * C_ + ggrp * 4 + 0) * N_ + id];
        pf1 = feat[((size_t)b2 * C_ + ggrp * 4 + 1) * N_ + id];
        pf2 = feat[((size_t)b2 * C_ + ggrp * 4 + 2) * N_ + id];
        pf3 = feat[((size_t)b2 * C_ + ggrp * 4 + 3) * N_ + id];
      } else if (ggrp == 8){
        const int id = idx[(size_t)g2 * 32 + grow];
        size_t pb = ((size_t)b2 * N_ + id) * 3;
        prx = __fsub_rn(xyz[pb + 0], newxyz[(size_t)g2 * 3 + 0]);
        pry = __fsub_rn(xyz[pb + 1], newxyz[(size_t)g2 * 3 + 1]);
        prz = __fsub_rn(xyz[pb + 2], newxyz[(size_t)g2 * 3 + 2]);
      }
    }
  };
  auto commit_xs = [&](int buf){
    float* xr = &sm[L::XS + buf * (32 * 36) + grow * 36];
    if constexpr (FT){
      if (ggrp < 4){
        xr[3 + ggrp * 8 + 0] = bflo(pfeat.x); xr[3 + ggrp * 8 + 1] = bfhi(pfeat.x);
        xr[3 + ggrp * 8 + 2] = bflo(pfeat.y); xr[3 + ggrp * 8 + 3] = bfhi(pfeat.y);
        xr[3 + ggrp * 8 + 4] = bflo(pfeat.z); xr[3 + ggrp * 8 + 5] = bfhi(pfeat.z);
        xr[3 + ggrp * 8 + 6] = bflo(pfeat.w); xr[3 + ggrp * 8 + 7] = bfhi(pfeat.w);
      } else if (ggrp == 4){
        xr[0] = prx; xr[1] = pry; xr[2] = prz; xr[35] = 0.f;
      }
    } else {
      if (ggrp < 8){
        xr[3 + ggrp * 4 + 0] = pf0; xr[3 + ggrp * 4 + 1] = pf1;
        xr[3 + ggrp * 4 + 2] = pf2; xr[3 + ggrp * 4 + 3] = pf3;
      } else if (ggrp == 8){
        xr[0] = prx; xr[1] = pry; xr[2] = prz; xr[35] = 0.f;
      }
    }
  };

  prefetch(0);
  commit_xs(0);
  __syncthreads();    // covers weights + xs(0)

  for (int it = 0; it < 32; ++it){
    const int g = blockIdx.x * 32 + it;
    const int b = g >> 10;
    const int xbuf = (DEPTH == 1) ? (it & 1) : 0;
    if (it < 31) prefetch(it + 1);              // issue next group's loads

    // ---- mm1: rows {rb, rb+16} x outs {og*2, og*2+1} ----
    const int xbase = L::XS + xbuf * (32 * 36);
    float a00 = 0.f, a01 = 0.f, a10 = 0.f, a11 = 0.f;
#pragma unroll 3
    for (int cb = 0; cb < 36; cb += 4){
      const float4 x0 = *(const float4*)&sm[xbase + rb * 36 + cb];
      const float4 x1 = *(const float4*)&sm[xbase + (rb + 16) * 36 + cb];
      const float4 w0 = *(const float4*)&sm[L::W1O + (og * 2 + 0) * 36 + cb];
      const float4 w1 = *(const float4*)&sm[L::W1O + (og * 2 + 1) * 36 + cb];
      a00 = fmaf(x0.x, w0.x, a00); a00 = fmaf(x0.y, w0.y, a00);
      a00 = fmaf(x0.z, w0.z, a00); a00 = fmaf(x0.w, w0.w, a00);
      a01 = fmaf(x0.x, w1.x, a01); a01 = fmaf(x0.y, w1.y, a01);
      a01 = fmaf(x0.z, w1.z, a01); a01 = fmaf(x0.w, w1.w, a01);
      a10 = fmaf(x1.x, w0.x, a10); a10 = fmaf(x1.y, w0.y, a10);
      a10 = fmaf(x1.z, w0.z, a10); a10 = fmaf(x1.w, w0.w, a10);
      a11 = fmaf(x1.x, w1.x, a11); a11 = fmaf(x1.y, w1.y, a11);
      a11 = fmaf(x1.z, w1.z, a11); a11 = fmaf(x1.w, w1.w, a11);
    }
    if constexpr (DEPTH == 1){
      stS[0] += a00 + a10; stQ[0] = fmaf(a00, a00, stQ[0]); stQ[0] = fmaf(a10, a10, stQ[0]);
      stS[1] += a01 + a11; stQ[1] = fmaf(a01, a01, stQ[1]); stQ[1] = fmaf(a11, a11, stQ[1]);
      if (it < 31) commit_xs(xbuf ^ 1);         // disjoint buffer: no hazard
      __syncthreads();                          // xs(it+1) visible; WAR ordered
      continue;
    }

    // ---- bn1 + relu -> hA ----
    sm[L::HA + rb * 68 + og * 2 + 0]        = fmaxf(fmaf(a00, sa1[0], sb1[0]), 0.f);
    sm[L::HA + rb * 68 + og * 2 + 1]        = fmaxf(fmaf(a01, sa1[1], sb1[1]), 0.f);
    sm[L::HA + (rb + 16) * 68 + og * 2 + 0] = fmaxf(fmaf(a10, sa1[0], sb1[0]), 0.f);
    sm[L::HA + (rb + 16) * 68 + og * 2 + 1] = fmaxf(fmaf(a11, sa1[1], sb1[1]), 0.f);
    __syncthreads();                            // HA ready; xs dead
    if (it < 31) commit_xs(0);                  // overlap with mm2/mm3

    // ---- mm2: rows {rb, rb+16} x outs {og*2, og*2+1}, W2 swizzled ----
    float c00 = 0.f, c01 = 0.f, c10 = 0.f, c11 = 0.f;
#pragma unroll 4
    for (int cb = 0; cb < 64; cb += 4){
      const float4 x0 = *(const float4*)&sm[L::HA + rb * 68 + cb];
      const float4 x1 = *(const float4*)&sm[L::HA + (rb + 16) * 68 + cb];
      const int r0 = og * 2 + 0, r1 = og * 2 + 1;
      const float4 w0 = *(const float4*)&sm[L::W2O + (r0 << 6) + (((cb >> 2) ^ ((r0 >> 1) & 3)) << 2)];
      const float4 w1 = *(const float4*)&sm[L::W2O + (r1 << 6) + (((cb >> 2) ^ ((r1 >> 1) & 3)) << 2)];
      c00 = fmaf(x0.x, w0.x, c00); c00 = fmaf(x0.y, w0.y, c00);
      c00 = fmaf(x0.z, w0.z, c00); c00 = fmaf(x0.w, w0.w, c00);
      c01 = fmaf(x0.x, w1.x, c01); c01 = fmaf(x0.y, w1.y, c01);
      c01 = fmaf(x0.z, w1.z, c01); c01 = fmaf(x0.w, w1.w, c01);
      c10 = fmaf(x1.x, w0.x, c10); c10 = fmaf(x1.y, w0.y, c10);
      c10 = fmaf(x1.z, w0.z, c10); c10 = fmaf(x1.w, w0.w, c10);
      c11 = fmaf(x1.x, w1.x, c11); c11 = fmaf(x1.y, w1.y, c11);
      c11 = fmaf(x1.z, w1.z, c11); c11 = fmaf(x1.w, w1.w, c11);
    }
    if constexpr (DEPTH == 2){
      stS[0] += c00 + c10; stQ[0] = fmaf(c00, c00, stQ[0]); stQ[0] = fmaf(c10, c10, stQ[0]);
      stS[1] += c01 + c11; stQ[1] = fmaf(c01, c01, stQ[1]); stQ[1] = fmaf(c11, c11, stQ[1]);
      __syncthreads();                          // orders xs commit + HA reuse
      continue;
    }

    if constexpr (DEPTH == 3){
      // ---- bn2 + relu -> hB ----
      sm[L::HB + rb * 68 + og * 2 + 0]        = fmaxf(fmaf(c00, sa2[0], sb2[0]), 0.f);
      sm[L::HB + rb * 68 + og * 2 + 1]        = fmaxf(fmaf(c01, sa2[1], sb2[1]), 0.f);
      sm[L::HB + (rb + 16) * 68 + og * 2 + 0] = fmaxf(fmaf(c10, sa2[0], sb2[0]), 0.f);
      sm[L::HB + (rb + 16) * 68 + og * 2 + 1] = fmaxf(fmaf(c11, sa2[1], sb2[1]), 0.f);
      __syncthreads();                          // HB ready; xs commit visible

      // ---- mm3: rows {rb, rb+16} x outs {og*4..og*4+3}, W3 swizzled ----
      float d0[4] = {0.f, 0.f, 0.f, 0.f};
      float d1[4] = {0.f, 0.f, 0.f, 0.f};
#pragma unroll 2
      for (int cb = 0; cb < 64; cb += 4){
        const float4 x0 = *(const float4*)&sm[L::HB + rb * 68 + cb];
        const float4 x1 = *(const float4*)&sm[L::HB + (rb + 16) * 68 + cb];
#pragma unroll
        for (int u = 0; u < 4; u++){
          const int r = og * 4 + u;
          const float4 wv = *(const float4*)&sm[L::W3O + (r << 6) + (((cb >> 2) ^ ((r >> 2) & 3)) << 2)];
          d0[u] = fmaf(x0.x, wv.x, d0[u]); d0[u] = fmaf(x0.y, wv.y, d0[u]);
          d0[u] = fmaf(x0.z, wv.z, d0[u]); d0[u] = fmaf(x0.w, wv.w, d0[u]);
          d1[u] = fmaf(x1.x, wv.x, d1[u]); d1[u] = fmaf(x1.y, wv.y, d1[u]);
          d1[u] = fmaf(x1.z, wv.z, d1[u]); d1[u] = fmaf(x1.w, wv.w, d1[u]);
        }
      }
#pragma unroll
      for (int u = 0; u < 4; u++){
        stS[u] += d0[u] + d1[u];
        stQ[u] = fmaf(d0[u], d0[u], stQ[u]);
        stQ[u] = fmaf(d1[u], d1[u], stQ[u]);
      }

      // ---- pre-BN max/min over the 32 rows (16 rb lanes x 2 rows) ----
      const int s = g & 1023;
#pragma unroll
      for (int u = 0; u < 4; u++){
        float mx = fmaxf(d0[u], d1[u]);
        float mn = fminf(d0[u], d1[u]);
#pragma unroll
        for (int m = 1; m < 16; m <<= 1){
          mx = fmaxf(mx, __shfl_xor(mx, m));
          mn = fminf(mn, __shfl_xor(mn, m));
        }
        if (rb == 0){
          size_t o = ((size_t)b * 128 + og * 4 + u) * 1024 + s;
          m3max[o] = f2bf(mx); m3min[o] = f2bf(mn);
        }
      }
    }
  }

  // ---- block stats partials: reduce over the 16 rb lanes ----
#pragma unroll
  for (int m = 1; m < 16; m <<= 1){
#pragma unroll
    for (int u = 0; u < US; u++){
      stS[u] += __shfl_xor(stS[u], m);
      stQ[u] += __shfl_xor(stQ[u], m);
    }
  }
  if (rb == 0){
    constexpr int CH = (DEPTH == 3) ? 128 : 64;
    float* p = partials + (size_t)blockIdx.x * (2 * CH);
    const int o0 = og * US;
#pragma unroll
    for (int u = 0; u < US; u++){ p[o0 + u] = stS[u]; p[CH + o0 + u] = stQ[u]; }
  }
}

// ---- stats stage 2: reduce 512 partial rows, emit per-channel scale/shift ----
template<int CH>
__global__ __launch_bounds__(256) void stats_fin(const float* __restrict__ partials,
                                                 const float* __restrict__ g,
                                                 const float* __restrict__ bet,
                                                 float* __restrict__ sab){
  const int t = threadIdx.x;
  __shared__ float red[2 * CH];
  if (t < 2 * CH){
    float a = 0.f;
#pragma unroll 8
    for (int r = 0; r < 512; r++) a += partials[(size_t)r * (2 * CH) + t];
    red[t] = a;
  }
  __syncthreads();
  if (t < CH){
    constexpr float inv = 1.f / (float)((size_t)B_ * S_ * K_);
    float mean = red[t] * inv;
    float var  = red[CH + t] * inv - mean * mean;
    float r    = 1.f / sqrtf(var + BN_EPS_);
    float a    = r * g[t];
    sab[t] = a;
    sab[CH + t] = bet[t] - mean * a;
  }
}

// ---- final: bn3(+relu) on bf16 pre-BN max/min (monotone-affine dispatch) ----
__global__ __launch_bounds__(256) void final_kernel(const unsigned short* __restrict__ m3max,
                                                    const unsigned short* __restrict__ m3min,
                                                    const float* __restrict__ sab3,
                                                    float* __restrict__ outNF){
  const int q = blockIdx.x * 256 + threadIdx.x;   // quad index over B*128*1024/4
  const int e = q * 4;
  const int o = (e >> 10) & 127;
  const float a = sab3[o], c = sab3[128 + o];
  const ushort4 mx = ((const ushort4*)m3max)[q];
  const ushort4 mn = ((const ushort4*)m3min)[q];
  float4 r;
  r.x = fmaxf(fmaf(bfu(a >= 0.f ? mx.x : mn.x), a, c), 0.f);
  r.y = fmaxf(fmaf(bfu(a >= 0.f ? mx.y : mn.y), a, c), 0.f);
  r.z = fmaxf(fmaf(bfu(a >= 0.f ? mx.z : mn.z), a, c), 0.f);
  r.w = fmaxf(fmaf(bfu(a >= 0.f ? mx.w : mn.w), a, c), 0.f);
  ((float4*)outNF)[q] = r;
}

extern "C" void kernel_launch(void* const* d_in, const int* in_sizes, int n_in,
                              void* d_out, int out_size, void* d_ws, size_t ws_size,
                              hipStream_t stream){
  (void)in_sizes; (void)n_in; (void)out_size;
  const float* xyz = (const float*)d_in[0];
  const float* feat = (const float*)d_in[1];
  const float* W1 = (const float*)d_in[2];
  const float* g1 = (const float*)d_in[3];
  const float* b1 = (const float*)d_in[4];
  const float* W2 = (const float*)d_in[5];
  const float* g2 = (const float*)d_in[6];
  const float* b2 = (const float*)d_in[7];
  const float* W3 = (const float*)d_in[8];
  const float* g3 = (const float*)d_in[9];
  const float* b3 = (const float*)d_in[10];

  float* newxyz = (float*)d_out;                       // (B,S,3)
  float* outNF  = newxyz + (size_t)B_ * S_ * 3;        // (B,128,S)
  char* ws = (char*)d_ws;

  size_t off = 0;
  auto alloc = [&](size_t bytes){ size_t o = off; off += (bytes + 255) & ~(size_t)255; return o; };
  size_t o_idx  = alloc((size_t)B_ * S_ * K_ * 4);           // 2 MB
  size_t o_part = alloc((size_t)512 * 256 * 4);              // 512 KB
  size_t o_sab1 = alloc(1024);
  size_t o_sab2 = alloc(1024);
  size_t o_sab3 = alloc(1024);
  size_t o_m3mx = alloc((size_t)B_ * S_ * 128 * 2);          // 4 MB (bf16)
  size_t o_m3mn = alloc((size_t)B_ * S_ * 128 * 2);          // 4 MB (bf16)
  size_t o_featT = alloc((size_t)B_ * N_ * C_ * 2);          // 8 MB (bf16)
  const bool ft = ws_size >= off;                            // 19.4 MB total

  int*   idxp  = (int*)(ws + o_idx);
  float* part  = (float*)(ws + o_part);
  float* sab1  = (float*)(ws + o_sab1);
  float* sab2  = (float*)(ws + o_sab2);
  float* sab3  = (float*)(ws + o_sab3);
  unsigned short* m3mx  = (unsigned short*)(ws + o_m3mx);
  unsigned short* m3mn  = (unsigned short*)(ws + o_m3mn);
  unsigned short* featT = (unsigned short*)(ws + o_featT);

  // fused FPS (blocks 0-15) + feat transpose (blocks 16..4111, hidden under FPS)
  fps_trans_kernel<<<ft ? 4112 : 16, 256, 0, stream>>>(xyz, newxyz, feat, featT);
  ballq_kernel<<<B_ * S_ / 4, 256, 0, stream>>>(xyz, newxyz, idxp);

  if (ft){
    pass_kernel<1, true><<<512, 512, 0, stream>>>(xyz, feat, featT, newxyz, idxp,
        W1, W2, W3, sab1, sab2, part, m3mx, m3mn);
    stats_fin<64><<<1, 256, 0, stream>>>(part, g1, b1, sab1);
    pass_kernel<2, true><<<512, 512, 0, stream>>>(xyz, feat, featT, newxyz, idxp,
        W1, W2, W3, sab1, sab2, part, m3mx, m3mn);
    stats_fin<64><<<1, 256, 0, stream>>>(part, g2, b2, sab2);
    pass_kernel<3, true><<<512, 512, 0, stream>>>(xyz, feat, featT, newxyz, idxp,
        W1, W2, W3, sab1, sab2, part, m3mx, m3mn);
    stats_fin<128><<<1, 256, 0, stream>>>(part, g3, b3, sab3);
  } else {
    pass_kernel<1, false><<<512, 512, 0, stream>>>(xyz, feat, featT, newxyz, idxp,
        W1, W2, W3, sab1, sab2, part, m3mx, m3mn);
    stats_fin<64><<<1, 256, 0, stream>>>(part, g1, b1, sab1);
    pass_kernel<2, false><<<512, 512, 0, stream>>>(xyz, feat, featT, newxyz, idxp,
        W1, W2, W3, sab1, sab2, part, m3mx, m3mn);
    stats_fin<64><<<1, 256, 0, stream>>>(part, g2, b2, sab2);
    pass_kernel<3, false><<<512, 512, 0, stream>>>(xyz, feat, featT, newxyz, idxp,
        W1, W2, W3, sab1, sab2, part, m3mx, m3mn);
    stats_fin<128><<<1, 256, 0, stream>>>(part, g3, b3, sab3);
  }
  final_kernel<<<(B_ * 128 * S_) / 1024, 256, 0, stream>>>(m3mx, m3mn, sab3, outNF);
}

// Round 19
// 1445.795 us; speedup vs baseline: 1.0433x; 1.0307x over previous
//
#include <hip/hip_runtime.h>
#include <hip/hip_bf16.h>

// ---- problem constants ----
static constexpr int B_ = 16;
static constexpr int N_ = 8192;
static constexpr int C_ = 32;     // input feature channels
static constexpr int S_ = 1024;   // NPOINT
static constexpr int K_ = 32;     // NSAMPLE
static constexpr float BN_EPS_ = 1e-5f;

typedef float f32x2 __attribute__((ext_vector_type(2)));

__device__ __forceinline__ unsigned short f2bf(float f){
  unsigned u = __float_as_uint(f);
  unsigned r = (u + 0x7fffu + ((u >> 16) & 1u)) >> 16;
  return (unsigned short)r;
}
__device__ __forceinline__ float bflo(unsigned u){ return __int_as_float(u << 16); }
__device__ __forceinline__ float bfhi(unsigned u){ return __int_as_float(u & 0xffff0000u); }
__device__ __forceinline__ float bfu(unsigned short u){ return __int_as_float(((unsigned)u) << 16); }

// rocPRIM-standard wave64 DPP reduce step on a u64 key (HW-proven R9-R18).
template<int CTRL>
__device__ __forceinline__ unsigned long long dpp64(unsigned long long v){
  int lo = (int)(unsigned)(v & 0xffffffffull);
  int hi = (int)(unsigned)(v >> 32);
  int lo2 = __builtin_amdgcn_update_dpp(lo, lo, CTRL, 0xf, 0xf, false);
  int hi2 = __builtin_amdgcn_update_dpp(hi, hi, CTRL, 0xf, 0xf, false);
  return (((unsigned long long)(unsigned)hi2) << 32) | (unsigned)lo2;
}
__device__ __forceinline__ unsigned long long u64max(unsigned long long a,
                                                     unsigned long long b){
  return a > b ? a : b;
}

// ---- fused FPS + transpose (R18 HW-proven, byte-identical) ----
__global__ __launch_bounds__(256) void fps_trans_kernel(
    const float* __restrict__ xyz, float* __restrict__ newxyz,
    const float* __restrict__ feat, unsigned short* __restrict__ featT){
  __shared__ float pl[N_ * 3];                    // FPS: batch copy; T: tile
  __shared__ unsigned long long slots[2][4];      // [parity][wave]

  if (blockIdx.x >= 16){
    // ---- transpose role ----
    const int tb = blockIdx.x - 16;               // [0,4096)
    const int b = tb >> 8;
    const int n0 = (tb & 255) * 32;
    const int tx = threadIdx.x & 31, ty = threadIdx.x >> 5;
#pragma unroll
    for (int i = 0; i < 4; i++){
      int c = ty + i * 8;
      pl[c * 33 + tx] = feat[((size_t)b * C_ + c) * N_ + n0 + tx];
    }
    __syncthreads();
#pragma unroll
    for (int i = 0; i < 4; i++){
      int r = ty + i * 8;
      featT[((size_t)b * N_ + n0 + r) * C_ + tx] = f2bf(pl[tx * 33 + r]);
    }
    return;
  }

  // ---- FPS role (exact R16 body: descending recovery scan) ----
  const int b = blockIdx.x, t = threadIdx.x;      // t in [0,256)
  const float* px = xyz + (size_t)b * N_ * 3;

  for (int i = t; i < N_ * 3 / 4; i += 256)
    ((float4*)pl)[i] = ((const float4*)px)[i];

  f32x2 X2[16], Y2[16], Z2[16], MD2[16];
#pragma unroll
  for (int q = 0; q < 16; q++){
    const int p0 = 512 * q + t, p1 = 512 * q + 256 + t;
    float x0 = px[3 * p0 + 0], y0 = px[3 * p0 + 1], z0 = px[3 * p0 + 2];
    float x1 = px[3 * p1 + 0], y1 = px[3 * p1 + 1], z1 = px[3 * p1 + 2];
    asm volatile("" : "+v"(x0), "+v"(y0), "+v"(z0),
                      "+v"(x1), "+v"(y1), "+v"(z1));   // pin SCALARS in VGPRs
    X2[q] = f32x2{x0, x1};
    Y2[q] = f32x2{y0, y1};
    Z2[q] = f32x2{z0, z1};
    MD2[q] = f32x2{1e10f, 1e10f};
  }
  if (t == 0){
    size_t o = (size_t)b * S_ * 3;
    newxyz[o] = px[0]; newxyz[o + 1] = px[1]; newxyz[o + 2] = px[2];
  }
  float cx = px[0], cy = px[1], cz = px[2];
  __syncthreads();                                // covers pl copy

  for (int i = 1; i < S_; i++){
    const int p = i & 1;
    const f32x2 cx2 = {cx, cx}, cy2 = {cy, cy}, cz2 = {cz, cz};
    float tmax = -1.f;
#pragma unroll
    for (int q = 0; q < 16; q++){
      f32x2 dx = X2[q] - cx2;                     // per-half rn sub
      f32x2 dy = Y2[q] - cy2;
      f32x2 dz = Z2[q] - cz2;
      f32x2 dd = (dx * dx + dy * dy) + dz * dz;   // exact reference op order
      f32x2 m;
      m[0] = fminf(MD2[q][0], dd[0]);
      m[1] = fminf(MD2[q][1], dd[1]);
      MD2[q] = m;
      tmax = fmaxf(tmax, fmaxf(m[0], m[1]));      // v_max3-fusable
    }
    // recover this thread's FIRST (smallest global) index attaining tmax:
    // descending q, high half before low half -> later (smaller) overwrite.
    unsigned cand = 0;
#pragma unroll
    for (int q = 15; q >= 0; q--){
      if (MD2[q][1] == tmax) cand = (unsigned)(512 * q + 256 + t);
      if (MD2[q][0] == tmax) cand = (unsigned)(512 * q + t);
    }
    // key: larger value wins; tie -> larger (8191-idx) -> smaller idx.
    unsigned long long key = ((unsigned long long)__float_as_uint(tmax) << 32)
                           | (unsigned long long)(8191u - cand);
    key = u64max(key, dpp64<0xb1>(key));          // quad_perm [1,0,3,2]
    key = u64max(key, dpp64<0x4e>(key));          // quad_perm [2,3,0,1]
    key = u64max(key, dpp64<0x114>(key));         // row_shr:4
    key = u64max(key, dpp64<0x118>(key));         // row_shr:8
    key = u64max(key, dpp64<0x142>(key));         // row_bcast:15
    key = u64max(key, dpp64<0x143>(key));         // row_bcast:31
    if ((t & 63) == 63) slots[p][t >> 6] = key;   // plain write, 1 per wave
    __syncthreads();
    unsigned long long best = u64max(u64max(slots[p][0], slots[p][1]),
                                     u64max(slots[p][2], slots[p][3]));
    const int fi = 8191 - (int)(best & 0xffffu);
    cx = pl[3 * fi]; cy = pl[3 * fi + 1]; cz = pl[3 * fi + 2];  // LDS broadcast
    if (t == 0){
      size_t o = ((size_t)b * S_ + i) * 3;
      newxyz[o] = cx; newxyz[o + 1] = cy; newxyz[o + 2] = cz;
    }
  }
}

// ---- ball query: 1 wave per centroid ----
__global__ __launch_bounds__(256) void ballq_kernel(const float* __restrict__ xyz,
                                                    const float* __restrict__ newxyz,
                                                    int* __restrict__ idxout){
  const int wave = threadIdx.x >> 6, lane = threadIdx.x & 63;
  const int cid = blockIdx.x * 4 + wave;
  const int b = cid >> 10;
  const float cx = newxyz[(size_t)cid * 3];
  const float cy = newxyz[(size_t)cid * 3 + 1];
  const float cz = newxyz[(size_t)cid * 3 + 2];
  const float* px = xyz + (size_t)b * N_ * 3;
  __shared__ int buf[4][32];
  const float r2 = 0.04f;   // fp32(double(0.2*0.2)) == 0x3D23D70A
  int have = 0;
  for (int base = 0; base < N_ && have < 32; base += 64){
    int p = base + lane;
    float dx = __fsub_rn(cx, px[3 * p]);
    float dy = __fsub_rn(cy, px[3 * p + 1]);
    float dz = __fsub_rn(cz, px[3 * p + 2]);
    float sq = __fadd_rn(__fadd_rn(__fmul_rn(dx, dx), __fmul_rn(dy, dy)), __fmul_rn(dz, dz));
    bool pred = sq < r2;
    unsigned long long m = __ballot(pred);
    if (pred){
      int pos = have + __popcll(m & ((1ull << lane) - 1ull));
      if (pos < 32) buf[wave][pos] = p;
    }
    have += (int)__popcll(m);
  }
  __syncthreads();
  if (lane < 32){
    int first = buf[wave][0];
    int v = (lane < have) ? buf[wave][lane] : first;
    idxout[(size_t)cid * 32 + lane] = v;
  }
}

// ---- LDS arena layout for the recompute pass kernels (all f32) ----
template<int DEPTH>
struct PassLds {
  static constexpr int XSBUF = (DEPTH == 1) ? 2 : 1;
  static constexpr int XS  = 0;                       // [XSBUF][32][36] f32
  static constexpr int W1O = XS + XSBUF * 32 * 36;    // [64][36] f32 (col35 zeroed)
  static constexpr int HA  = W1O + 64 * 36;           // [32][68] f32 (DEPTH>=2)
  static constexpr int W2O = HA + 32 * 68;            // [64][64] f32, chunk-XOR swizzled
  static constexpr int HB  = W2O + 64 * 64;           // [32][68] f32 (DEPTH==3)
  static constexpr int W3O = HB + 32 * 68;            // [128][64] f32, chunk-XOR swizzled
  static constexpr int FLOATS = (DEPTH == 1) ? (W1O + 64 * 36)
                             : (DEPTH == 2) ? (W2O + 64 * 64)
                             : (W3O + 128 * 64);      // D3: 20096 floats = 80384 B
};

// ---- fused recompute pass (256 threads, 4-row register blocking) ----
// Gather mapping: grow = t&31, ggrp = t>>5 in [0,8). Compute mapping:
// rb = t&7, og = t>>3 in [0,32); each thread computes rows
// {rb, rb+8, rb+16, rb+24} x {2 (mm1/mm2) or 4 (mm3)} channels. LDS
// wave-insts drop ~29% vs the R16 2-row tiling (x reads become 8-lane
// broadcasts; weight reads amortize over 4 rows). W2/W3 keep the
// 16B-chunk XOR swizzle. Stats/min-max reduce over the 8 rb lanes.
template<int DEPTH, bool FT>
__global__ __launch_bounds__(256, 2) void pass_kernel(
    const float* __restrict__ xyz, const float* __restrict__ feat,
    const unsigned short* __restrict__ featT, const float* __restrict__ newxyz,
    const int* __restrict__ idx,
    const float* __restrict__ W1, const float* __restrict__ W2,
    const float* __restrict__ W3,
    const float* __restrict__ sab1, const float* __restrict__ sab2,
    float* __restrict__ partials,
    unsigned short* __restrict__ m3max, unsigned short* __restrict__ m3min){
  using L = PassLds<DEPTH>;
  __shared__ float sm[L::FLOATS];
  const int t = threadIdx.x;
  const int grow = t & 31, ggrp = t >> 5;   // gather mapping (ggrp in [0,8))
  const int rb = t & 7, og = t >> 3;        // compute mapping (og in [0,32))

  // ---- stage weights once per block ----
  for (int i = t; i < 64 * 36; i += 256){
    int o = i / 36, c = i - o * 36;
    sm[L::W1O + i] = (c < 35) ? W1[o * 35 + c] : 0.f;
  }
  if constexpr (DEPTH >= 2){
    for (int i = t; i < 64 * 64; i += 256){
      int r = i >> 6, c = i & 63;
      sm[L::W2O + (r << 6) + ((((c >> 2) ^ ((r >> 1) & 3)) << 2) | (c & 3))] = W2[i];
    }
  }
  if constexpr (DEPTH == 3){
    for (int i = t; i < 128 * 64; i += 256){
      int r = i >> 6, c = i & 63;
      sm[L::W3O + (r << 6) + ((((c >> 2) ^ ((r >> 2) & 3)) << 2) | (c & 3))] = W3[i];
    }
  }

  // ---- per-thread BN params ----
  float sa1[2], sb1[2], sa2[2], sb2[2];
  if constexpr (DEPTH >= 2){
#pragma unroll
    for (int u = 0; u < 2; u++){ sa1[u] = sab1[og * 2 + u]; sb1[u] = sab1[64 + og * 2 + u]; }
  }
  if constexpr (DEPTH == 3){
#pragma unroll
    for (int u = 0; u < 2; u++){ sa2[u] = sab2[og * 2 + u]; sb2[u] = sab2[64 + og * 2 + u]; }
  }

  constexpr int US = (DEPTH == 3) ? 4 : 2;     // stats channels per thread
  float stS[US], stQ[US];
#pragma unroll
  for (int u = 0; u < US; u++){ stS[u] = 0.f; stQ[u] = 0.f; }

  // ---- prefetch state (registers) ----
  uint4 pfeat = {0, 0, 0, 0};
  float pf0 = 0.f, pf1 = 0.f, pf2 = 0.f, pf3 = 0.f;
  float prx = 0.f, pry = 0.f, prz = 0.f;

  auto prefetch = [&](int it2){
    const int g2 = blockIdx.x * 32 + it2;
    const int b2 = g2 >> 10;
    if constexpr (FT){
      if (ggrp < 4){
        const int id = idx[(size_t)g2 * 32 + grow];
        pfeat = *(const uint4*)(featT + ((size_t)b2 * N_ + id) * C_ + ggrp * 8);
      } else if (ggrp == 4){
        const int id = idx[(size_t)g2 * 32 + grow];
        size_t pb = ((size_t)b2 * N_ + id) * 3;
        prx = __fsub_rn(xyz[pb + 0], newxyz[(size_t)g2 * 3 + 0]);
        pry = __fsub_rn(xyz[pb + 1], newxyz[(size_t)g2 * 3 + 1]);
        prz = __fsub_rn(xyz[pb + 2], newxyz[(size_t)g2 * 3 + 2]);
      }
    } else {
      if (ggrp < 8){
        const int id = idx[(size_t)g2 * 32 + grow];
        pf0 = feat[((size_t)b2 * C_ + ggrp * 4 + 0) * N_ + id];
        pf1 = feat[((size_t)b2 * C_ + ggrp * 4 + 1) * N_ + id];
        pf2 = feat[((size_t)b2 * C_ + ggrp * 4 + 2) * N_ + id];
        pf3 = feat[((size_t)b2 * C_ + ggrp * 4 + 3) * N_ + id];
      }
      if (ggrp == 0){   // non-FT: also fetch rel coords (separate regs)
        const int id = idx[(size_t)g2 * 32 + grow];
        size_t pb = ((size_t)b2 * N_ + id) * 3;
        prx = __fsub_rn(xyz[pb + 0], newxyz[(size_t)g2 * 3 + 0]);
        pry = __fsub_rn(xyz[pb + 1], newxyz[(size_t)g2 * 3 + 1]);
        prz = __fsub_rn(xyz[pb + 2], newxyz[(size_t)g2 * 3 + 2]);
      }
    }
  };
  auto commit_xs = [&](int buf){
    float* xr = &sm[L::XS + buf * (32 * 36) + grow * 36];
    if constexpr (FT){
      if (ggrp < 4){
        xr[3 + ggrp * 8 + 0] = bflo(pfeat.x); xr[3 + ggrp * 8 + 1] = bfhi(pfeat.x);
        xr[3 + ggrp * 8 + 2] = bflo(pfeat.y); xr[3 + ggrp * 8 + 3] = bfhi(pfeat.y);
        xr[3 + ggrp * 8 + 4] = bflo(pfeat.z); xr[3 + ggrp * 8 + 5] = bfhi(pfeat.z);
        xr[3 + ggrp * 8 + 6] = bflo(pfeat.w); xr[3 + ggrp * 8 + 7] = bfhi(pfeat.w);
      } else if (ggrp == 4){
        xr[0] = prx; xr[1] = pry; xr[2] = prz; xr[35] = 0.f;
      }
    } else {
      if (ggrp < 8){
        xr[3 + ggrp * 4 + 0] = pf0; xr[3 + ggrp * 4 + 1] = pf1;
        xr[3 + ggrp * 4 + 2] = pf2; xr[3 + ggrp * 4 + 3] = pf3;
      }
      if (ggrp == 0){
        xr[0] = prx; xr[1] = pry; xr[2] = prz; xr[35] = 0.f;
      }
    }
  };

  prefetch(0);
  commit_xs(0);
  __syncthreads();    // covers weights + xs(0)

  for (int it = 0; it < 32; ++it){
    const int g = blockIdx.x * 32 + it;
    const int b = g >> 10;
    const int xbuf = (DEPTH == 1) ? (it & 1) : 0;
    if (it < 31) prefetch(it + 1);              // issue next group's loads

    // ---- mm1: rows {rb,rb+8,rb+16,rb+24} x outs {og*2, og*2+1} ----
    const int xbase = L::XS + xbuf * (32 * 36);
    float a[4][2] = {{0.f,0.f},{0.f,0.f},{0.f,0.f},{0.f,0.f}};
#pragma unroll 3
    for (int cb = 0; cb < 36; cb += 4){
      float4 xv[4];
#pragma unroll
      for (int r = 0; r < 4; r++)
        xv[r] = *(const float4*)&sm[xbase + (rb + r * 8) * 36 + cb];
      const float4 w0 = *(const float4*)&sm[L::W1O + (og * 2 + 0) * 36 + cb];
      const float4 w1 = *(const float4*)&sm[L::W1O + (og * 2 + 1) * 36 + cb];
#pragma unroll
      for (int r = 0; r < 4; r++){
        a[r][0] = fmaf(xv[r].x, w0.x, a[r][0]); a[r][0] = fmaf(xv[r].y, w0.y, a[r][0]);
        a[r][0] = fmaf(xv[r].z, w0.z, a[r][0]); a[r][0] = fmaf(xv[r].w, w0.w, a[r][0]);
        a[r][1] = fmaf(xv[r].x, w1.x, a[r][1]); a[r][1] = fmaf(xv[r].y, w1.y, a[r][1]);
        a[r][1] = fmaf(xv[r].z, w1.z, a[r][1]); a[r][1] = fmaf(xv[r].w, w1.w, a[r][1]);
      }
    }
    if constexpr (DEPTH == 1){
#pragma unroll
      for (int u = 0; u < 2; u++){
#pragma unroll
        for (int r = 0; r < 4; r++){
          stS[u] += a[r][u];
          stQ[u] = fmaf(a[r][u], a[r][u], stQ[u]);
        }
      }
      if (it < 31) commit_xs(xbuf ^ 1);         // disjoint buffer: no hazard
      __syncthreads();                          // xs(it+1) visible; WAR ordered
      continue;
    }

    // ---- bn1 + relu -> hA ----
#pragma unroll
    for (int r = 0; r < 4; r++){
      sm[L::HA + (rb + r * 8) * 68 + og * 2 + 0] = fmaxf(fmaf(a[r][0], sa1[0], sb1[0]), 0.f);
      sm[L::HA + (rb + r * 8) * 68 + og * 2 + 1] = fmaxf(fmaf(a[r][1], sa1[1], sb1[1]), 0.f);
    }
    __syncthreads();                            // HA ready; xs dead
    if (it < 31) commit_xs(0);                  // overlap with mm2/mm3

    // ---- mm2: 4 rows x outs {og*2, og*2+1}, W2 swizzled ----
    float c[4][2] = {{0.f,0.f},{0.f,0.f},{0.f,0.f},{0.f,0.f}};
#pragma unroll 4
    for (int cb = 0; cb < 64; cb += 4){
      float4 xv[4];
#pragma unroll
      for (int r = 0; r < 4; r++)
        xv[r] = *(const float4*)&sm[L::HA + (rb + r * 8) * 68 + cb];
      const int r0 = og * 2 + 0, r1 = og * 2 + 1;
      const float4 w0 = *(const float4*)&sm[L::W2O + (r0 << 6) + (((cb >> 2) ^ ((r0 >> 1) & 3)) << 2)];
      const float4 w1 = *(const float4*)&sm[L::W2O + (r1 << 6) + (((cb >> 2) ^ ((r1 >> 1) & 3)) << 2)];
#pragma unroll
      for (int r = 0; r < 4; r++){
        c[r][0] = fmaf(xv[r].x, w0.x, c[r][0]); c[r][0] = fmaf(xv[r].y, w0.y, c[r][0]);
        c[r][0] = fmaf(xv[r].z, w0.z, c[r][0]); c[r][0] = fmaf(xv[r].w, w0.w, c[r][0]);
        c[r][1] = fmaf(xv[r].x, w1.x, c[r][1]); c[r][1] = fmaf(xv[r].y, w1.y, c[r][1]);
        c[r][1] = fmaf(xv[r].z, w1.z, c[r][1]); c[r][1] = fmaf(xv[r].w, w1.w, c[r][1]);
      }
    }
    if constexpr (DEPTH == 2){
#pragma unroll
      for (int u = 0; u < 2; u++){
#pragma unroll
        for (int r = 0; r < 4; r++){
          stS[u] += c[r][u];
          stQ[u] = fmaf(c[r][u], c[r][u], stQ[u]);
        }
      }
      __syncthreads();                          // orders xs commit + HA reuse
      continue;
    }

    if constexpr (DEPTH == 3){
      // ---- bn2 + relu -> hB ----
#pragma unroll
      for (int r = 0; r < 4; r++){
        sm[L::HB + (rb + r * 8) * 68 + og * 2 + 0] = fmaxf(fmaf(c[r][0], sa2[0], sb2[0]), 0.f);
        sm[L::HB + (rb + r * 8) * 68 + og * 2 + 1] = fmaxf(fmaf(c[r][1], sa2[1], sb2[1]), 0.f);
      }
      __syncthreads();                          // HB ready; xs commit visible

      // ---- mm3: 4 rows x outs {og*4..og*4+3}, W3 swizzled ----
      float d[4][4] = {{0.f,0.f,0.f,0.f},{0.f,0.f,0.f,0.f},
                       {0.f,0.f,0.f,0.f},{0.f,0.f,0.f,0.f}};
#pragma unroll 2
      for (int cb = 0; cb < 64; cb += 4){
        float4 xv[4];
#pragma unroll
        for (int r = 0; r < 4; r++)
          xv[r] = *(const float4*)&sm[L::HB + (rb + r * 8) * 68 + cb];
#pragma unroll
        for (int u = 0; u < 4; u++){
          const int wr = og * 4 + u;
          const float4 wv = *(const float4*)&sm[L::W3O + (wr << 6) + (((cb >> 2) ^ ((wr >> 2) & 3)) << 2)];
#pragma unroll
          for (int r = 0; r < 4; r++){
            d[r][u] = fmaf(xv[r].x, wv.x, d[r][u]); d[r][u] = fmaf(xv[r].y, wv.y, d[r][u]);
            d[r][u] = fmaf(xv[r].z, wv.z, d[r][u]); d[r][u] = fmaf(xv[r].w, wv.w, d[r][u]);
          }
        }
      }
#pragma unroll
      for (int u = 0; u < 4; u++){
#pragma unroll
        for (int r = 0; r < 4; r++){
          stS[u] += d[r][u];
          stQ[u] = fmaf(d[r][u], d[r][u], stQ[u]);
        }
      }

      // ---- pre-BN max/min over the 32 rows (8 rb lanes x 4 rows) ----
      const int s = g & 1023;
#pragma unroll
      for (int u = 0; u < 4; u++){
        float mx = fmaxf(fmaxf(d[0][u], d[1][u]), fmaxf(d[2][u], d[3][u]));
        float mn = fminf(fminf(d[0][u], d[1][u]), fminf(d[2][u], d[3][u]));
#pragma unroll
        for (int m = 1; m < 8; m <<= 1){
          mx = fmaxf(mx, __shfl_xor(mx, m));
          mn = fminf(mn, __shfl_xor(mn, m));
        }
        if (rb == 0){
          size_t o = ((size_t)b * 128 + og * 4 + u) * 1024 + s;
          m3max[o] = f2bf(mx); m3min[o] = f2bf(mn);
        }
      }
    }
  }

  // ---- block stats partials: reduce over the 8 rb lanes ----
#pragma unroll
  for (int m = 1; m < 8; m <<= 1){
#pragma unroll
    for (int u = 0; u < US; u++){
      stS[u] += __shfl_xor(stS[u], m);
      stQ[u] += __shfl_xor(stQ[u], m);
    }
  }
  if (rb == 0){
    constexpr int CH = (DEPTH == 3) ? 128 : 64;
    float* p = partials + (size_t)blockIdx.x * (2 * CH);
    const int o0 = og * US;
#pragma unroll
    for (int u = 0; u < US; u++){ p[o0 + u] = stS[u]; p[CH + o0 + u] = stQ[u]; }
  }
}

// ---- stats stage 2: reduce 512 partial rows, emit per-channel scale/shift ----
template<int CH>
__global__ __launch_bounds__(256) void stats_fin(const float* __restrict__ partials,
                                                 const float* __restrict__ g,
                                                 const float* __restrict__ bet,
                                                 float* __restrict__ sab){
  const int t = threadIdx.x;
  __shared__ float red[2 * CH];
  if (t < 2 * CH){
    float a = 0.f;
#pragma unroll 8
    for (int r = 0; r < 512; r++) a += partials[(size_t)r * (2 * CH) + t];
    red[t] = a;
  }
  __syncthreads();
  if (t < CH){
    constexpr float inv = 1.f / (float)((size_t)B_ * S_ * K_);
    float mean = red[t] * inv;
    float var  = red[CH + t] * inv - mean * mean;
    float r    = 1.f / sqrtf(var + BN_EPS_);
    float a    = r * g[t];
    sab[t] = a;
    sab[CH + t] = bet[t] - mean * a;
  }
}

// ---- final: bn3(+relu) on bf16 pre-BN max/min (monotone-affine dispatch) ----
__global__ __launch_bounds__(256) void final_kernel(const unsigned short* __restrict__ m3max,
                                                    const unsigned short* __restrict__ m3min,
                                                    const float* __restrict__ sab3,
                                                    float* __restrict__ outNF){
  const int q = blockIdx.x * 256 + threadIdx.x;   // quad index over B*128*1024/4
  const int e = q * 4;
  const int o = (e >> 10) & 127;
  const float a = sab3[o], c = sab3[128 + o];
  const ushort4 mx = ((const ushort4*)m3max)[q];
  const ushort4 mn = ((const ushort4*)m3min)[q];
  float4 r;
  r.x = fmaxf(fmaf(bfu(a >= 0.f ? mx.x : mn.x), a, c), 0.f);
  r.y = fmaxf(fmaf(bfu(a >= 0.f ? mx.y : mn.y), a, c), 0.f);
  r.z = fmaxf(fmaf(bfu(a >= 0.f ? mx.z : mn.z), a, c), 0.f);
  r.w = fmaxf(fmaf(bfu(a >= 0.f ? mx.w : mn.w), a, c), 0.f);
  ((float4*)outNF)[q] = r;
}

extern "C" void kernel_launch(void* const* d_in, const int* in_sizes, int n_in,
                              void* d_out, int out_size, void* d_ws, size_t ws_size,
                              hipStream_t stream){
  (void)in_sizes; (void)n_in; (void)out_size;
  const float* xyz = (const float*)d_in[0];
  const float* feat = (const float*)d_in[1];
  const float* W1 = (const float*)d_in[2];
  const float* g1 = (const float*)d_in[3];
  const float* b1 = (const float*)d_in[4];
  const float* W2 = (const float*)d_in[5];
  const float* g2 = (const float*)d_in[6];
  const float* b2 = (const float*)d_in[7];
  const float* W3 = (const float*)d_in[8];
  const float* g3 = (const float*)d_in[9];
  const float* b3 = (const float*)d_in[10];

  float* newxyz = (float*)d_out;                       // (B,S,3)
  float* outNF  = newxyz + (size_t)B_ * S_ * 3;        // (B,128,S)
  char* ws = (char*)d_ws;

  size_t off = 0;
  auto alloc = [&](size_t bytes){ size_t o = off; off += (bytes + 255) & ~(size_t)255; return o; };
  size_t o_idx  = alloc((size_t)B_ * S_ * K_ * 4);           // 2 MB
  size_t o_part = alloc((size_t)512 * 256 * 4);              // 512 KB
  size_t o_sab1 = alloc(1024);
  size_t o_sab2 = alloc(1024);
  size_t o_sab3 = alloc(1024);
  size_t o_m3mx = alloc((size_t)B_ * S_ * 128 * 2);          // 4 MB (bf16)
  size_t o_m3mn = alloc((size_t)B_ * S_ * 128 * 2);          // 4 MB (bf16)
  size_t o_featT = alloc((size_t)B_ * N_ * C_ * 2);          // 8 MB (bf16)
  const bool ft = ws_size >= off;                            // 19.4 MB total

  int*   idxp  = (int*)(ws + o_idx);
  float* part  = (float*)(ws + o_part);
  float* sab1  = (float*)(ws + o_sab1);
  float* sab2  = (float*)(ws + o_sab2);
  float* sab3  = (float*)(ws + o_sab3);
  unsigned short* m3mx  = (unsigned short*)(ws + o_m3mx);
  unsigned short* m3mn  = (unsigned short*)(ws + o_m3mn);
  unsigned short* featT = (unsigned short*)(ws + o_featT);

  // fused FPS (blocks 0-15) + feat transpose (blocks 16..4111, hidden under FPS)
  fps_trans_kernel<<<ft ? 4112 : 16, 256, 0, stream>>>(xyz, newxyz, feat, featT);
  ballq_kernel<<<B_ * S_ / 4, 256, 0, stream>>>(xyz, newxyz, idxp);

  if (ft){
    pass_kernel<1, true><<<512, 256, 0, stream>>>(xyz, feat, featT, newxyz, idxp,
        W1, W2, W3, sab1, sab2, part, m3mx, m3mn);
    stats_fin<64><<<1, 256, 0, stream>>>(part, g1, b1, sab1);
    pass_kernel<2, true><<<512, 256, 0, stream>>>(xyz, feat, featT, newxyz, idxp,
        W1, W2, W3, sab1, sab2, part, m3mx, m3mn);
    stats_fin<64><<<1, 256, 0, stream>>>(part, g2, b2, sab2);
    pass_kernel<3, true><<<512, 256, 0, stream>>>(xyz, feat, featT, newxyz, idxp,
        W1, W2, W3, sab1, sab2, part, m3mx, m3mn);
    stats_fin<128><<<1, 256, 0, stream>>>(part, g3, b3, sab3);
  } else {
    pass_kernel<1, false><<<512, 256, 0, stream>>>(xyz, feat, featT, newxyz, idxp,
        W1, W2, W3, sab1, sab2, part, m3mx, m3mn);
    stats_fin<64><<<1, 256, 0, stream>>>(part, g1, b1, sab1);
    pass_kernel<2, false><<<512, 256, 0, stream>>>(xyz, feat, featT, newxyz, idxp,
        W1, W2, W3, sab1, sab2, part, m3mx, m3mn);
    stats_fin<64><<<1, 256, 0, stream>>>(part, g2, b2, sab2);
    pass_kernel<3, false><<<512, 256, 0, stream>>>(xyz, feat, featT, newxyz, idxp,
        W1, W2, W3, sab1, sab2, part, m3mx, m3mn);
    stats_fin<128><<<1, 256, 0, stream>>>(part, g3, b3, sab3);
  }
  final_kernel<<<(B_ * 128 * S_) / 1024, 256, 0, stream>>>(m3mx, m3mn, sab3, outNF);
}